// Round 5
// baseline (79.431 us; speedup 1.0000x reference)
//
#include <hip/hip_runtime.h>

// PathSampling: per node, score 32 paths (sum of centrality over masked
// prefix), stable top-8, emit selected masked paths + their edge rows.
//
// Round 5: ILP restructure. One wave per node; lanes 0-31 carry path elems
// 0-3, lanes 32-63 carry elems 4-7 (half the gather chain per lane, numpy
// pairwise sum preserved via one shfl_xor). Rank computed from an LDS
// broadcast row (8 ds_read_b128) instead of 32 ds_bpermute. All winner/edge
// copies are single wave-wide instructions. No __syncthreads (intra-wave
// LDS only, program-ordered).

#define N_NODE   100000
#define N_PATH   32
#define L_PATH   8
#define K_PATH   8

typedef int   v4i __attribute__((ext_vector_type(4)));
typedef float v4f __attribute__((ext_vector_type(4)));

__global__ __launch_bounds__(256) void path_sampling_kernel(
    const int*   __restrict__ paths,
    const int*   __restrict__ edge_ids,
    const int*   __restrict__ rand_lens,
    const float* __restrict__ centrality,
    int*         __restrict__ out_paths,   // [N_NODE, K_PATH, L_PATH]
    int*         __restrict__ out_edges)   // [N_NODE, K_PATH, L_PATH-1]
{
    __shared__ float ssc[4][32];   // per-wave score row
    __shared__ int   wsrc[4][8];   // per-wave winner source path per rank

    const int t    = threadIdx.x;
    const int wv   = t >> 6;                    // wave in block (0..3)
    const int lane = t & 63;
    const int half = lane >> 5;                 // 0: elems 0-3, 1: elems 4-7
    const int p    = lane & 31;                 // path within node
    const int node = blockIdx.x * 4 + wv;       // grid*4 == N_NODE exactly

    const size_t row = (size_t)node * N_PATH + p;

    // One coalesced b128 per lane: this lane's 4 path elements.
    // Wave covers 2KB contiguous (node's full 32x8 int row-pair).
    v4i mp4 = ((const v4i*)paths)[row * 2 + half];
    int len = rand_lens[row];                   // keep positions j <= len

    int mp[4] = {mp4.x, mp4.y, mp4.z, mp4.w};

    // Mask + predicated gather (4 per lane instead of 8).
    const int jb = half * 4;
    float c[4];
    #pragma unroll
    for (int k = 0; k < 4; ++k) {
        if (jb + k > len) mp[k] = -1;
        c[k] = (mp[k] < 0) ? 0.0f : centrality[mp[k]];
    }

    // numpy pairwise tree: half0 -> (c0+c1)+(c2+c3), half1 -> (c4+c5)+(c6+c7),
    // combined with one cross-half shuffle. fp add is bit-commutative, so
    // ps+other matches ((lo)+(hi)) exactly on both halves.
    const float ps    = (c[0] + c[1]) + (c[2] + c[3]);
    const float other = __shfl_xor(ps, 32);
    const float s     = ps + other;

    // Publish scores to this wave's LDS row (half0 lanes suffice), then
    // every lane reads all 32 back via broadcast b128 reads. Intra-wave DS
    // ops complete in program order; no barrier needed.
    if (!half) ssc[wv][p] = s;
    v4f sc[8];
    #pragma unroll
    for (int i = 0; i < 8; ++i) sc[i] = ((const v4f*)ssc[wv])[i];

    // Stable descending rank (ties -> lower index wins), matches lax.top_k.
    const unsigned ltm = (1u << p) - 1u;        // bit j set iff j < p
    int rank = 0;
    #pragma unroll
    for (int j = 0; j < 32; ++j) {
        const float sj = sc[j >> 2][j & 3];
        rank += (sj > s) || ((sj == s) && ((ltm >> j) & 1u));
    }

    // Winner outputs: 8 ranks x 2 halves = 16 lanes store 16B each into a
    // 256B contiguous region -> one coalesced store instruction.
    if (rank < K_PATH) {
        const size_t obase = (size_t)node * K_PATH + rank;
        v4i m = {mp[0], mp[1], mp[2], mp[3]};
        ((v4i*)out_paths)[obase * 2 + half] = m;
        if (!half) wsrc[wv][rank] = p;          // publish winner src row
    }

    // Cooperative edge copy: 8 selected rows x 7 ints = 56 ints per node,
    // one dword per lane (lanes 0-55): 1 load + 1 store instruction.
    const int* ebase = edge_ids + (size_t)node * (N_PATH * (L_PATH - 1));
    int*       edst  = out_edges + (size_t)node * (K_PATH * (L_PATH - 1));
    if (lane < 56) {
        const int r    = lane / 7;              // compiler magic-mul
        const int col  = lane - r * 7;
        const int srow = wsrc[wv][r];
        edst[lane] = ebase[srow * 7 + col];
    }
}

extern "C" void kernel_launch(void* const* d_in, const int* in_sizes, int n_in,
                              void* d_out, int out_size, void* d_ws, size_t ws_size,
                              hipStream_t stream) {
    const int*   paths      = (const int*)  d_in[0];
    const int*   edge_ids   = (const int*)  d_in[1];
    const int*   rand_lens  = (const int*)  d_in[2];
    const float* centrality = (const float*)d_in[3];
    // d_in[4] is k_path (scalar, known == 8)

    int* out_paths = (int*)d_out;
    int* out_edges = out_paths + (size_t)N_NODE * K_PATH * L_PATH;

    const int nodes_per_block = 4;   // 256 threads = 4 waves = 4 nodes
    const int grid = N_NODE / nodes_per_block;  // 25000, exact

    path_sampling_kernel<<<grid, 256, 0, stream>>>(
        paths, edge_ids, rand_lens, centrality, out_paths, out_edges);
}

// Round 6
// 78.286 us; speedup vs baseline: 1.0146x; 1.0146x over previous
//
#include <hip/hip_runtime.h>

// PathSampling: per node, score 32 paths (sum of centrality over masked
// prefix), stable top-8, emit selected masked paths + their edge rows.
//
// Round 5: ILP restructure. One wave per node; lanes 0-31 carry path elems
// 0-3, lanes 32-63 carry elems 4-7 (half the gather chain per lane, numpy
// pairwise sum preserved via one shfl_xor). Rank computed from an LDS
// broadcast row (8 ds_read_b128) instead of 32 ds_bpermute. All winner/edge
// copies are single wave-wide instructions. No __syncthreads (intra-wave
// LDS only, program-ordered).

#define N_NODE   100000
#define N_PATH   32
#define L_PATH   8
#define K_PATH   8

typedef int   v4i __attribute__((ext_vector_type(4)));
typedef float v4f __attribute__((ext_vector_type(4)));

__global__ __launch_bounds__(256) void path_sampling_kernel(
    const int*   __restrict__ paths,
    const int*   __restrict__ edge_ids,
    const int*   __restrict__ rand_lens,
    const float* __restrict__ centrality,
    int*         __restrict__ out_paths,   // [N_NODE, K_PATH, L_PATH]
    int*         __restrict__ out_edges)   // [N_NODE, K_PATH, L_PATH-1]
{
    __shared__ float ssc[4][32];   // per-wave score row
    __shared__ int   wsrc[4][8];   // per-wave winner source path per rank

    const int t    = threadIdx.x;
    const int wv   = t >> 6;                    // wave in block (0..3)
    const int lane = t & 63;
    const int half = lane >> 5;                 // 0: elems 0-3, 1: elems 4-7
    const int p    = lane & 31;                 // path within node
    const int node = blockIdx.x * 4 + wv;       // grid*4 == N_NODE exactly

    const size_t row = (size_t)node * N_PATH + p;

    // One coalesced b128 per lane: this lane's 4 path elements.
    // Wave covers 2KB contiguous (node's full 32x8 int row-pair).
    v4i mp4 = ((const v4i*)paths)[row * 2 + half];
    int len = rand_lens[row];                   // keep positions j <= len

    int mp[4] = {mp4.x, mp4.y, mp4.z, mp4.w};

    // Mask + predicated gather (4 per lane instead of 8).
    const int jb = half * 4;
    float c[4];
    #pragma unroll
    for (int k = 0; k < 4; ++k) {
        if (jb + k > len) mp[k] = -1;
        c[k] = (mp[k] < 0) ? 0.0f : centrality[mp[k]];
    }

    // numpy pairwise tree: half0 -> (c0+c1)+(c2+c3), half1 -> (c4+c5)+(c6+c7),
    // combined with one cross-half shuffle. fp add is bit-commutative, so
    // ps+other matches ((lo)+(hi)) exactly on both halves.
    const float ps    = (c[0] + c[1]) + (c[2] + c[3]);
    const float other = __shfl_xor(ps, 32);
    const float s     = ps + other;

    // Publish scores to this wave's LDS row (half0 lanes suffice), then
    // every lane reads all 32 back via broadcast b128 reads. Intra-wave DS
    // ops complete in program order; no barrier needed.
    if (!half) ssc[wv][p] = s;
    v4f sc[8];
    #pragma unroll
    for (int i = 0; i < 8; ++i) sc[i] = ((const v4f*)ssc[wv])[i];

    // Stable descending rank (ties -> lower index wins), matches lax.top_k.
    const unsigned ltm = (1u << p) - 1u;        // bit j set iff j < p
    int rank = 0;
    #pragma unroll
    for (int j = 0; j < 32; ++j) {
        const float sj = sc[j >> 2][j & 3];
        rank += (sj > s) || ((sj == s) && ((ltm >> j) & 1u));
    }

    // Winner outputs: 8 ranks x 2 halves = 16 lanes store 16B each into a
    // 256B contiguous region -> one coalesced store instruction.
    if (rank < K_PATH) {
        const size_t obase = (size_t)node * K_PATH + rank;
        v4i m = {mp[0], mp[1], mp[2], mp[3]};
        ((v4i*)out_paths)[obase * 2 + half] = m;
        if (!half) wsrc[wv][rank] = p;          // publish winner src row
    }

    // Cooperative edge copy: 8 selected rows x 7 ints = 56 ints per node,
    // one dword per lane (lanes 0-55): 1 load + 1 store instruction.
    const int* ebase = edge_ids + (size_t)node * (N_PATH * (L_PATH - 1));
    int*       edst  = out_edges + (size_t)node * (K_PATH * (L_PATH - 1));
    if (lane < 56) {
        const int r    = lane / 7;              // compiler magic-mul
        const int col  = lane - r * 7;
        const int srow = wsrc[wv][r];
        edst[lane] = ebase[srow * 7 + col];
    }
}

extern "C" void kernel_launch(void* const* d_in, const int* in_sizes, int n_in,
                              void* d_out, int out_size, void* d_ws, size_t ws_size,
                              hipStream_t stream) {
    const int*   paths      = (const int*)  d_in[0];
    const int*   edge_ids   = (const int*)  d_in[1];
    const int*   rand_lens  = (const int*)  d_in[2];
    const float* centrality = (const float*)d_in[3];
    // d_in[4] is k_path (scalar, known == 8)

    int* out_paths = (int*)d_out;
    int* out_edges = out_paths + (size_t)N_NODE * K_PATH * L_PATH;

    const int nodes_per_block = 4;   // 256 threads = 4 waves = 4 nodes
    const int grid = N_NODE / nodes_per_block;  // 25000, exact

    path_sampling_kernel<<<grid, 256, 0, stream>>>(
        paths, edge_ids, rand_lens, centrality, out_paths, out_edges);
}

// Round 7
// 76.450 us; speedup vs baseline: 1.0390x; 1.0240x over previous
//
#include <hip/hip_runtime.h>

// PathSampling: per node, score 32 paths (sum of centrality over masked
// prefix), stable top-8, emit selected masked paths + their edge rows.
//
// Round 5: ILP restructure. One wave per node; lanes 0-31 carry path elems
// 0-3, lanes 32-63 carry elems 4-7 (half the gather chain per lane, numpy
// pairwise sum preserved via one shfl_xor). Rank computed from an LDS
// broadcast row (8 ds_read_b128) instead of 32 ds_bpermute. All winner/edge
// copies are single wave-wide instructions. No __syncthreads (intra-wave
// LDS only, program-ordered).

#define N_NODE   100000
#define N_PATH   32
#define L_PATH   8
#define K_PATH   8

typedef int   v4i __attribute__((ext_vector_type(4)));
typedef float v4f __attribute__((ext_vector_type(4)));

__global__ __launch_bounds__(256) void path_sampling_kernel(
    const int*   __restrict__ paths,
    const int*   __restrict__ edge_ids,
    const int*   __restrict__ rand_lens,
    const float* __restrict__ centrality,
    int*         __restrict__ out_paths,   // [N_NODE, K_PATH, L_PATH]
    int*         __restrict__ out_edges)   // [N_NODE, K_PATH, L_PATH-1]
{
    __shared__ float ssc[4][32];   // per-wave score row
    __shared__ int   wsrc[4][8];   // per-wave winner source path per rank

    const int t    = threadIdx.x;
    const int wv   = t >> 6;                    // wave in block (0..3)
    const int lane = t & 63;
    const int half = lane >> 5;                 // 0: elems 0-3, 1: elems 4-7
    const int p    = lane & 31;                 // path within node
    const int node = blockIdx.x * 4 + wv;       // grid*4 == N_NODE exactly

    const size_t row = (size_t)node * N_PATH + p;

    // One coalesced b128 per lane: this lane's 4 path elements.
    // Wave covers 2KB contiguous (node's full 32x8 int row-pair).
    v4i mp4 = ((const v4i*)paths)[row * 2 + half];
    int len = rand_lens[row];                   // keep positions j <= len

    int mp[4] = {mp4.x, mp4.y, mp4.z, mp4.w};

    // Mask + predicated gather (4 per lane instead of 8).
    const int jb = half * 4;
    float c[4];
    #pragma unroll
    for (int k = 0; k < 4; ++k) {
        if (jb + k > len) mp[k] = -1;
        c[k] = (mp[k] < 0) ? 0.0f : centrality[mp[k]];
    }

    // numpy pairwise tree: half0 -> (c0+c1)+(c2+c3), half1 -> (c4+c5)+(c6+c7),
    // combined with one cross-half shuffle. fp add is bit-commutative, so
    // ps+other matches ((lo)+(hi)) exactly on both halves.
    const float ps    = (c[0] + c[1]) + (c[2] + c[3]);
    const float other = __shfl_xor(ps, 32);
    const float s     = ps + other;

    // Publish scores to this wave's LDS row (half0 lanes suffice), then
    // every lane reads all 32 back via broadcast b128 reads. Intra-wave DS
    // ops complete in program order; no barrier needed.
    if (!half) ssc[wv][p] = s;
    v4f sc[8];
    #pragma unroll
    for (int i = 0; i < 8; ++i) sc[i] = ((const v4f*)ssc[wv])[i];

    // Stable descending rank (ties -> lower index wins), matches lax.top_k.
    const unsigned ltm = (1u << p) - 1u;        // bit j set iff j < p
    int rank = 0;
    #pragma unroll
    for (int j = 0; j < 32; ++j) {
        const float sj = sc[j >> 2][j & 3];
        rank += (sj > s) || ((sj == s) && ((ltm >> j) & 1u));
    }

    // Winner outputs: 8 ranks x 2 halves = 16 lanes store 16B each into a
    // 256B contiguous region -> one coalesced store instruction.
    if (rank < K_PATH) {
        const size_t obase = (size_t)node * K_PATH + rank;
        v4i m = {mp[0], mp[1], mp[2], mp[3]};
        ((v4i*)out_paths)[obase * 2 + half] = m;
        if (!half) wsrc[wv][rank] = p;          // publish winner src row
    }

    // Cooperative edge copy: 8 selected rows x 7 ints = 56 ints per node,
    // one dword per lane (lanes 0-55): 1 load + 1 store instruction.
    const int* ebase = edge_ids + (size_t)node * (N_PATH * (L_PATH - 1));
    int*       edst  = out_edges + (size_t)node * (K_PATH * (L_PATH - 1));
    if (lane < 56) {
        const int r    = lane / 7;              // compiler magic-mul
        const int col  = lane - r * 7;
        const int srow = wsrc[wv][r];
        edst[lane] = ebase[srow * 7 + col];
    }
}

extern "C" void kernel_launch(void* const* d_in, const int* in_sizes, int n_in,
                              void* d_out, int out_size, void* d_ws, size_t ws_size,
                              hipStream_t stream) {
    const int*   paths      = (const int*)  d_in[0];
    const int*   edge_ids   = (const int*)  d_in[1];
    const int*   rand_lens  = (const int*)  d_in[2];
    const float* centrality = (const float*)d_in[3];
    // d_in[4] is k_path (scalar, known == 8)

    int* out_paths = (int*)d_out;
    int* out_edges = out_paths + (size_t)N_NODE * K_PATH * L_PATH;

    const int nodes_per_block = 4;   // 256 threads = 4 waves = 4 nodes
    const int grid = N_NODE / nodes_per_block;  // 25000, exact

    path_sampling_kernel<<<grid, 256, 0, stream>>>(
        paths, edge_ids, rand_lens, centrality, out_paths, out_edges);
}